// Round 2
// baseline (1622.226 us; speedup 1.0000x reference)
//
#include <hip/hip_runtime.h>
#include <stdint.h>

// Problem constants (fixed-shape problem)
#define N_NODES 50000
#define N_EDGES 200000
#define N_GRAPH 64
#define F_IN    1536
#define H_DIM   1024
#define C_OUT   80
#define FUSE_D  1024
#define POOL_CHUNK 128
#define MLP1_KC 320   // 2560 / 8 k-chunks

typedef unsigned short u16;
typedef short s16x8 __attribute__((ext_vector_type(8)));
typedef float f32x4 __attribute__((ext_vector_type(4)));
typedef unsigned short u16x4 __attribute__((ext_vector_type(4)));
typedef unsigned short u16x8 __attribute__((ext_vector_type(8)));

// ---------- bf16 helpers (bit-level, RNE) ----------
__device__ __forceinline__ float bf2f(u16 u) {
    union { unsigned int i; float f; } v; v.i = ((unsigned int)u) << 16; return v.f;
}
__device__ __forceinline__ u16 f2bf(float f) {
    union { float f; unsigned int i; } v; v.f = f;
    unsigned int x = v.i;
    unsigned int r = (x + 0x7fffu + ((x >> 16) & 1u)) >> 16;
    return (u16)r;
}

// async global->LDS, 16 bytes per lane (lds dest must be linear in lane order)
__device__ __forceinline__ void load_lds16(const void* g, void* l) {
    __builtin_amdgcn_global_load_lds(
        (const __attribute__((address_space(1))) void*)g,
        (__attribute__((address_space(3))) void*)l, 16, 0, 0);
}

// ---------- graph prep kernels ----------
__global__ void k_deg(const int* __restrict__ dst, int* cnt) {
    int e = blockIdx.x * blockDim.x + threadIdx.x;
    if (e < N_EDGES) atomicAdd(&cnt[dst[e]], 1);
}

__global__ void k_cg(const int* __restrict__ batch, int* cG) {
    int i = blockIdx.x * blockDim.x + threadIdx.x;
    if (i < N_NODES) atomicAdd(&cG[batch[i]], 1);
}

// single-block exclusive scan of cnt -> rowptr, plus dis = rsqrt(deg+1)
__global__ __launch_bounds__(1024) void k_scan(const int* __restrict__ cnt,
                                               int* __restrict__ rowptr,
                                               float* __restrict__ dis) {
    __shared__ int lds[1024];
    int t = threadIdx.x;
    const int CH = (N_NODES + 1023) / 1024;  // 49
    int beg = t * CH, end = min(beg + CH, N_NODES);
    int s = 0;
    for (int i = beg; i < end; ++i) s += cnt[i];
    lds[t] = s;
    __syncthreads();
    for (int off = 1; off < 1024; off <<= 1) {
        int v = (t >= off) ? lds[t - off] : 0;
        __syncthreads();
        lds[t] += v;
        __syncthreads();
    }
    int run = lds[t] - s;  // exclusive prefix
    for (int i = beg; i < end; ++i) {
        rowptr[i] = run;
        int c = cnt[i];
        run += c;
        dis[i] = rsqrtf((float)(c + 1));  // +1 self-loop; deg>=1 always
    }
    if (t == 1023) rowptr[N_NODES] = lds[1023];
}

__global__ void k_fill(const int* __restrict__ src, const int* __restrict__ dst,
                       const int* __restrict__ rowptr, int* cursor, int* col) {
    int e = blockIdx.x * blockDim.x + threadIdx.x;
    if (e < N_EDGES) {
        int d = dst[e];
        int p = atomicAdd(&cursor[d], 1);
        col[rowptr[d] + p] = src[e];
    }
}

// ---------- fp32 -> bf16 cast (vectorized) ----------
__global__ void k_cvt(const float* __restrict__ in, u16* __restrict__ out, long n) {
    long i = (long)blockIdx.x * blockDim.x + threadIdx.x;
    long stride = (long)gridDim.x * blockDim.x;
    for (long v = i * 4; v < n; v += stride * 4) {
        float4 f = *(const float4*)(in + v);
        u16x4 o = { f2bf(f.x), f2bf(f.y), f2bf(f.z), f2bf(f.w) };
        *(u16x4*)(out + v) = o;
    }
}

// W [K x Nn] fp32 -> Wt [Nn x K] bf16 (tiled transpose)
__global__ void k_trn(const float* __restrict__ W, u16* __restrict__ Wt, int K, int Nn) {
    __shared__ float tle[32][33];
    int n0 = blockIdx.x * 32, k0 = blockIdx.y * 32;
    int tx = threadIdx.x, ty = threadIdx.y;  // 32 x 8
    for (int i = ty; i < 32; i += 8)
        tle[i][tx] = W[(size_t)(k0 + i) * Nn + n0 + tx];
    __syncthreads();
    for (int i = ty; i < 32; i += 8)
        Wt[(size_t)(n0 + i) * K + k0 + tx] = f2bf(tle[tx][i]);
}

// ---------- MFMA GEMM: C[Mx1024] = A[MxK] @ Bt[1024xK]^T, all bf16, C bf16 ----------
// 256x256 block tile, BK=64, 512 threads = 8 waves (2M x 4N), per-wave 128x64.
//
// Staging (T3+T4): 2 LDS buffers, depth-2 prefetch via global_load_lds; counted
// s_waitcnt vmcnt(8) at the top of each K-tile (drain-to-0 only on the final peel).
// Raw s_barrier throughout (__syncthreads would force vmcnt(0)).
//
// K-tile body (m196/m201 fine interleave): 4 phases of 16 MFMA each, with
// read-ahead-1 register ping-pong (afA/afB, bvA/bvB). Each phase:
//   barrier -> lgkmcnt(0)+sched_barrier (waits only last phase's reads)
//   -> issue NEXT phase's ds_reads -> setprio(1) -> 16 MFMA -> setprio(0).
// The next phase's ds_reads run in the LDS pipe concurrently with this phase's
// MFMAs in the matrix pipe -- the two pipes overlap instead of alternating
// (previous coarse structure: 24 reads, full drain, 64 MFMA = serial).
// Correctness barriers: B0 (after vmcnt, before first read of fresh buffer) and
// B5 (after every wave's last lgkm of this buffer, before stage overwrites it).
//
// T2 swizzle: LDS dest lane-linear (global_load_lds constraint); 16B chunk at
// slot s of row r holds global k-chunk kc = s ^ (r&7); reads use slot kc^(r&7).
// T1: grid = 196*4 = 784 = 8*98 -> clean XCD swizzle, A-panel sharers same XCD.
__global__ __launch_bounds__(512) void gemm_bt(const u16* __restrict__ A,
                                               const u16* __restrict__ Bt,
                                               u16* __restrict__ C,
                                               int M, int Nn, int K) {
    // 2 buffers x 2048 chunks x 8 bf16 = 64 KiB each
    __shared__ __attribute__((aligned(16))) u16 ldsA[2 * 2048 * 8];
    __shared__ __attribute__((aligned(16))) u16 ldsB[2 * 2048 * 8];

    int bid = blockIdx.x;
    int swz = (bid & 7) * 98 + (bid >> 3);
    int bN = swz & 3;          // 4 N-tiles (Nn = 1024)
    int bM = swz >> 2;         // 196 M-tiles

    int tid = threadIdx.x;
    int lane = tid & 63, wave = tid >> 6;
    int wm = wave >> 2, wn = wave & 3;     // 2 x 4 wave grid
    int qd = lane >> 4, lo = lane & 15;

    // staging pointers: 4 A-chunks + 4 B-chunks per thread per K-tile.
    const u16* ga[4];
    const u16* gb[4];
#pragma unroll
    for (int r = 0; r < 4; ++r) {
        int c = r * 512 + tid;
        int row = c >> 3;
        int kc = (c & 7) ^ (row & 7);
        int gr = bM * 256 + row;
        if (gr > M - 1) gr = M - 1;        // clamp; garbage rows masked at store
        ga[r] = A + (size_t)gr * K + kc * 8;
        gb[r] = Bt + (size_t)(bN * 256 + row) * K + kc * 8;
    }

    auto stage = [&](int buf) {
        int base = buf * 16384;            // elems
#pragma unroll
        for (int r = 0; r < 4; ++r) {
            load_lds16(ga[r], &ldsA[base + (r * 512 + tid) * 8]);
            ga[r] += 64;                   // next K-tile (+128 B)
        }
#pragma unroll
        for (int r = 0; r < 4; ++r) {
            load_lds16(gb[r], &ldsB[base + (r * 512 + tid) * 8]);
            gb[r] += 64;
        }
    };

    const int NKT = K >> 6;                // 24 (K=1536) / 16 (K=1024)
    f32x4 acc[8][4] = {};

    // prologue: tiles 0 and 1 in flight (16 loads/thread)
    stage(0);
    stage(1);

    const int soff0 = (qd ^ (lo & 7)) * 8;          // swizzled 16B slot, ks=0
    const int soff1 = ((4 + qd) ^ (lo & 7)) * 8;    // ks=1

    for (int kt = 0; kt < NKT; ++kt) {
        int cur = kt & 1;
        if (kt < NKT - 1) {
            asm volatile("s_waitcnt vmcnt(8)" ::: "memory");  // tile kt landed; kt+1 in flight
        } else {
            asm volatile("s_waitcnt vmcnt(0)" ::: "memory");  // final peel: drain
        }
        __builtin_amdgcn_s_barrier();       // B0: tile kt resident for all waves

        const u16* lA = ldsA + cur * 16384;
        const u16* lB = ldsB + cur * 16384;

        s16x8 afA[4], afB[4], bvA[4], bvB[4];
        // pre-reads for phase 0: B(ks0) + A(ks0, rows 0..63 of wave half)
#pragma unroll
        for (int i = 0; i < 4; ++i)
            bvA[i] = *(const s16x8*)&lB[(wn * 64 + i * 16 + lo) * 64 + soff0];
#pragma unroll
        for (int i = 0; i < 4; ++i)
            afA[i] = *(const s16x8*)&lA[(wm * 128 + i * 16 + lo) * 64 + soff0];

        // ---- phase 0: acc[0..3] += A(ks0,m0..3) x B(ks0) ----
        __builtin_amdgcn_s_barrier();
        asm volatile("s_waitcnt lgkmcnt(0)" ::: "memory");
        __builtin_amdgcn_sched_barrier(0);
        // read-ahead p1: A(ks0, rows 64..127)
#pragma unroll
        for (int i = 0; i < 4; ++i)
            afB[i] = *(const s16x8*)&lA[(wm * 128 + (4 + i) * 16 + lo) * 64 + soff0];
        __builtin_amdgcn_s_setprio(1);
#pragma unroll
        for (int i = 0; i < 4; ++i)
#pragma unroll
            for (int nf = 0; nf < 4; ++nf)
                acc[i][nf] = __builtin_amdgcn_mfma_f32_16x16x32_bf16(afA[i], bvA[nf], acc[i][nf], 0, 0, 0);
        __builtin_amdgcn_s_setprio(0);

        // ---- phase 1: acc[4..7] += A(ks0,m4..7) x B(ks0) ----
        __builtin_amdgcn_s_barrier();
        asm volatile("s_waitcnt lgkmcnt(0)" ::: "memory");
        __builtin_amdgcn_sched_barrier(0);
        // read-ahead p2: B(ks1) + A(ks1, rows 0..63)
#pragma unroll
        for (int i = 0; i < 4; ++i)
            bvB[i] = *(const s16x8*)&lB[(wn * 64 + i * 16 + lo) * 64 + soff1];
#pragma unroll
        for (int i = 0; i < 4; ++i)
            afA[i] = *(const s16x8*)&lA[(wm * 128 + i * 16 + lo) * 64 + soff1];
        __builtin_amdgcn_s_setprio(1);
#pragma unroll
        for (int i = 0; i < 4; ++i)
#pragma unroll
            for (int nf = 0; nf < 4; ++nf)
                acc[4 + i][nf] = __builtin_amdgcn_mfma_f32_16x16x32_bf16(afB[i], bvA[nf], acc[4 + i][nf], 0, 0, 0);
        __builtin_amdgcn_s_setprio(0);

        // ---- phase 2: acc[0..3] += A(ks1,m0..3) x B(ks1) ----
        __builtin_amdgcn_s_barrier();
        asm volatile("s_waitcnt lgkmcnt(0)" ::: "memory");
        __builtin_amdgcn_sched_barrier(0);
        // read-ahead p3: A(ks1, rows 64..127)
#pragma unroll
        for (int i = 0; i < 4; ++i)
            afB[i] = *(const s16x8*)&lA[(wm * 128 + (4 + i) * 16 + lo) * 64 + soff1];
        __builtin_amdgcn_s_setprio(1);
#pragma unroll
        for (int i = 0; i < 4; ++i)
#pragma unroll
            for (int nf = 0; nf < 4; ++nf)
                acc[i][nf] = __builtin_amdgcn_mfma_f32_16x16x32_bf16(afA[i], bvB[nf], acc[i][nf], 0, 0, 0);
        __builtin_amdgcn_s_setprio(0);

        // ---- phase 3: acc[4..7] += A(ks1,m4..7) x B(ks1) ----
        __builtin_amdgcn_s_barrier();
        asm volatile("s_waitcnt lgkmcnt(0)" ::: "memory");
        __builtin_amdgcn_sched_barrier(0);
        __builtin_amdgcn_s_setprio(1);
#pragma unroll
        for (int i = 0; i < 4; ++i)
#pragma unroll
            for (int nf = 0; nf < 4; ++nf)
                acc[4 + i][nf] = __builtin_amdgcn_mfma_f32_16x16x32_bf16(afB[i], bvB[nf], acc[4 + i][nf], 0, 0, 0);
        __builtin_amdgcn_s_setprio(0);

        __builtin_amdgcn_s_barrier();       // B5: all waves' reads of buf done
        if (kt + 2 < NKT) stage(cur);       // prefetch tile kt+2 into freed buffer
    }

    // C/D layout: col = lane&15, row = quad*4 + reg  [verified m89/m91]
#pragma unroll
    for (int mf = 0; mf < 8; ++mf) {
        int rowb = bM * 256 + wm * 128 + mf * 16 + qd * 4;
#pragma unroll
        for (int nf = 0; nf < 4; ++nf) {
            int colI = bN * 256 + wn * 64 + nf * 16 + lo;
            f32x4 a = acc[mf][nf];
#pragma unroll
            for (int reg = 0; reg < 4; ++reg) {
                int row = rowb + reg;
                if (row < M) C[(size_t)row * Nn + colI] = f2bf(a[reg]);
            }
        }
    }
}

// ---------- GCN aggregation, wave-per-node: 4 nodes/block, 64 lanes x 16 feats ----
// out[i] = relu(dis_i^2*h[i] + sum_e dis_i*dis_src*h[src] + b)
__global__ __launch_bounds__(256) void k_agg(const u16* __restrict__ hin, u16* __restrict__ hout,
                                             const int* __restrict__ rowptr, const int* __restrict__ col,
                                             const float* __restrict__ dis, const float* __restrict__ bias) {
    int w = threadIdx.x >> 6, lane = threadIdx.x & 63;
    int i = blockIdx.x * 4 + w;            // N_NODES % 4 == 0
    float di = dis[i];
    int beg = rowptr[i], end = rowptr[i + 1];
    const u16* hrow = hin + (size_t)i * H_DIM + lane * 16;
    u16x8 v0 = *(const u16x8*)hrow;
    u16x8 v1 = *(const u16x8*)(hrow + 8);
    float w0 = di * di;
    float acc[16];
#pragma unroll
    for (int j = 0; j < 8; j++) { acc[j] = w0 * bf2f(v0[j]); acc[8 + j] = w0 * bf2f(v1[j]); }
    for (int e = beg; e < end; ++e) {
        int s = col[e];                     // wave-uniform
        float wgt = di * dis[s];
        const u16* nrow = hin + (size_t)s * H_DIM + lane * 16;
        u16x8 u0 = *(const u16x8*)nrow;
        u16x8 u1 = *(const u16x8*)(nrow + 8);
#pragma unroll
        for (int j = 0; j < 8; j++) { acc[j] += wgt * bf2f(u0[j]); acc[8 + j] += wgt * bf2f(u1[j]); }
    }
    const float* bp = bias + lane * 16;
    u16x8 o0, o1;
#pragma unroll
    for (int j = 0; j < 8; j++) {
        o0[j] = f2bf(fmaxf(acc[j] + bp[j], 0.f));
        o1[j] = f2bf(fmaxf(acc[8 + j] + bp[8 + j], 0.f));
    }
    u16* orow = hout + (size_t)i * H_DIM + lane * 16;
    *(u16x8*)orow = o0;
    *(u16x8*)(orow + 8) = o1;
}

// ---------- mean pool: chunked nodes, register segment-accumulate, atomic flush ----------
// grid: ceil(N/POOL_CHUNK) blocks x 256 threads (4 features each). batch sorted.
__global__ __launch_bounds__(256) void k_pool(const u16* __restrict__ h, const int* __restrict__ batch,
                                              float* __restrict__ pooled) {
    int t = threadIdx.x;
    int n0 = blockIdx.x * POOL_CHUNK;
    int n1 = min(n0 + POOL_CHUNK, N_NODES);
    float a0 = 0.f, a1 = 0.f, a2 = 0.f, a3 = 0.f;
    int curg = batch[n0];
    for (int n = n0; n < n1; ++n) {
        int g = batch[n];  // block-uniform
        if (g != curg) {   // uniform branch (rare: ~1-2 per block)
            float* p = &pooled[(size_t)curg * H_DIM + t * 4];
            atomicAdd(p + 0, a0); atomicAdd(p + 1, a1);
            atomicAdd(p + 2, a2); atomicAdd(p + 3, a3);
            a0 = a1 = a2 = a3 = 0.f;
            curg = g;
        }
        u16x4 v = *(const u16x4*)&h[(size_t)n * H_DIM + t * 4];
        a0 += bf2f(v[0]); a1 += bf2f(v[1]); a2 += bf2f(v[2]); a3 += bf2f(v[3]);
    }
    float* p = &pooled[(size_t)curg * H_DIM + t * 4];
    atomicAdd(p + 0, a0); atomicAdd(p + 1, a1);
    atomicAdd(p + 2, a2); atomicAdd(p + 3, a3);
}

// ---------- MLP head layer 1, split-K with atomic accumulation ----------
// grid: (16 gq, 4 jq, 8 kq); block 256. comb = [gx | pooled/count] per 4 graphs.
// hid accumulates raw (pre-bias, pre-relu); MLP2 applies bias+relu.
__global__ __launch_bounds__(256) void k_mlp1(const float* __restrict__ gx, const float* __restrict__ pooled,
                                              const int* __restrict__ cG,
                                              const float* __restrict__ fw1, float* __restrict__ hid) {
    __shared__ float comb[4 * MLP1_KC];
    int gq = blockIdx.x, jq = blockIdx.y, kq = blockIdx.z, t = threadIdx.x;
    int kbeg = kq * MLP1_KC;
    for (int idx = t; idx < 4 * MLP1_KC; idx += 256) {
        int gl = idx / MLP1_KC, kk = idx % MLP1_KC;
        int k = kbeg + kk;
        int g = gq * 4 + gl;
        float v;
        if (k < F_IN) v = gx[(size_t)g * F_IN + k];
        else v = pooled[(size_t)g * H_DIM + (k - F_IN)] / (float)max(cG[g], 1);
        comb[idx] = v;
    }
    __syncthreads();
    int j = jq * 256 + t;
    float a0 = 0, a1 = 0, a2 = 0, a3 = 0;
    for (int kk = 0; kk < MLP1_KC; ++kk) {
        float w = fw1[(size_t)(kbeg + kk) * FUSE_D + j];  // coalesced across lanes
        a0 += comb[kk] * w;
        a1 += comb[MLP1_KC + kk] * w;
        a2 += comb[2 * MLP1_KC + kk] * w;
        a3 += comb[3 * MLP1_KC + kk] * w;
    }
    atomicAdd(&hid[(size_t)(gq * 4 + 0) * FUSE_D + j], a0);
    atomicAdd(&hid[(size_t)(gq * 4 + 1) * FUSE_D + j], a1);
    atomicAdd(&hid[(size_t)(gq * 4 + 2) * FUSE_D + j], a2);
    atomicAdd(&hid[(size_t)(gq * 4 + 3) * FUSE_D + j], a3);
}

__global__ __launch_bounds__(128) void k_mlp2(const float* __restrict__ hid, const float* __restrict__ fb1,
                                              const float* __restrict__ fw2,
                                              const float* __restrict__ fb2, float* __restrict__ out) {
    __shared__ float hh[FUSE_D];
    int g = blockIdx.x, t = threadIdx.x;
    for (int idx = t; idx < FUSE_D; idx += 128)
        hh[idx] = fmaxf(hid[(size_t)g * FUSE_D + idx] + fb1[idx], 0.f);  // fused bias+relu
    __syncthreads();
    if (t < C_OUT) {
        float acc = fb2[t];
        for (int k = 0; k < FUSE_D; ++k) acc += hh[k] * fw2[k * C_OUT + t];
        out[g * C_OUT + t] = acc;
    }
}

extern "C" void kernel_launch(void* const* d_in, const int* in_sizes, int n_in,
                              void* d_out, int out_size, void* d_ws, size_t ws_size,
                              hipStream_t stream) {
    (void)in_sizes; (void)n_in; (void)out_size;
    const float* gx    = (const float*)d_in[0];
    const float* x     = (const float*)d_in[1];
    const int*   ei    = (const int*)d_in[2];
    const int*   batch = (const int*)d_in[3];
    const float* W1    = (const float*)d_in[4];
    const float* b1    = (const float*)d_in[5];
    const float* W2    = (const float*)d_in[6];
    const float* b2    = (const float*)d_in[7];
    const float* fw1   = (const float*)d_in[8];
    const float* fb1   = (const float*)d_in[9];
    const float* fw2   = (const float*)d_in[10];
    const float* fb2   = (const float*)d_in[11];
    float* out = (float*)d_out;
    const int* src = ei;
    const int* dst = ei + N_EDGES;

    // workspace layout (~366 MB total); zero zone at the end
    char* ws = (char*)d_ws;
    size_t off = 0;
    auto alloc = [&](size_t bytes) -> char* {
        char* p = ws + off;
        off += (bytes + 255) & ~(size_t)255;
        return p;
    };
    u16*  xb     = (u16*)alloc((size_t)N_NODES * F_IN * 2);   // reused as h2b
    u16*  h0b    = (u16*)alloc((size_t)N_NODES * H_DIM * 2);  // reused as h3b
    u16*  h1b    = (u16*)alloc((size_t)N_NODES * H_DIM * 2);
    u16*  W1T    = (u16*)alloc((size_t)H_DIM * F_IN * 2);
    u16*  W2T    = (u16*)alloc((size_t)H_DIM * H_DIM * 2);
    float* dis    = (float*)alloc((size_t)N_NODES * 4);
    int* rowptr   = (int*)alloc((size_t)(N_NODES + 1) * 4);
    int* col      = (int*)alloc((size_t)N_EDGES * 4);
    // ---- zero zone start ----
    int* cnt      = (int*)alloc((size_t)N_NODES * 4);
    int* cursor   = (int*)alloc((size_t)N_NODES * 4);
    int* cG       = (int*)alloc(256);
    float* pooled = (float*)alloc((size_t)N_GRAPH * H_DIM * 4);
    float* hid    = (float*)alloc((size_t)N_GRAPH * FUSE_D * 4);
    u16* h2b = xb;
    u16* h3b = h0b;
    (void)ws_size;

    // zero the accumulation zone (ws is poisoned 0xAA before every call)
    size_t zbytes = (size_t)((char*)(hid + N_GRAPH * FUSE_D) - (char*)cnt);
    hipMemsetAsync(cnt, 0, zbytes, stream);

    // graph prep
    k_deg<<<(N_EDGES + 255) / 256, 256, 0, stream>>>(dst, cnt);
    k_cg<<<(N_NODES + 255) / 256, 256, 0, stream>>>(batch, cG);
    k_scan<<<1, 1024, 0, stream>>>(cnt, rowptr, dis);
    k_fill<<<(N_EDGES + 255) / 256, 256, 0, stream>>>(src, dst, rowptr, cursor, col);

    // casts / weight transposes
    k_cvt<<<4096, 256, 0, stream>>>(x, xb, (long)N_NODES * F_IN);
    k_trn<<<dim3(H_DIM / 32, F_IN / 32), dim3(32, 8), 0, stream>>>(W1, W1T, F_IN, H_DIM);
    k_trn<<<dim3(H_DIM / 32, H_DIM / 32), dim3(32, 8), 0, stream>>>(W2, W2T, H_DIM, H_DIM);

    // GEMM grid: 196 M-tiles x 4 N-tiles = 784 blocks (784 % 8 == 0 -> clean XCD swizzle)
    const int GEMM_BLOCKS = ((N_NODES + 255) / 256) * (H_DIM / 256);   // 784

    // layer 1
    gemm_bt<<<GEMM_BLOCKS, 512, 0, stream>>>(xb, W1T, h0b, N_NODES, H_DIM, F_IN);
    k_agg<<<N_NODES / 4, 256, 0, stream>>>(h0b, h1b, rowptr, col, dis, b1);
    // layer 2
    gemm_bt<<<GEMM_BLOCKS, 512, 0, stream>>>(h1b, W2T, h2b, N_NODES, H_DIM, H_DIM);
    k_agg<<<N_NODES / 4, 256, 0, stream>>>(h2b, h3b, rowptr, col, dis, b2);

    // pool + head
    k_pool<<<(N_NODES + POOL_CHUNK - 1) / POOL_CHUNK, 256, 0, stream>>>(h3b, batch, pooled);
    k_mlp1<<<dim3(N_GRAPH / 4, FUSE_D / 256, 8), 256, 0, stream>>>(gx, pooled, cG, fw1, hid);
    k_mlp2<<<N_GRAPH, 128, 0, stream>>>(hid, fb1, fw2, fb2, out);
}

// Round 5
// 1499.942 us; speedup vs baseline: 1.0815x; 1.0815x over previous
//
#include <hip/hip_runtime.h>
#include <stdint.h>

// Problem constants (fixed-shape problem)
#define N_NODES 50000
#define N_EDGES 200000
#define N_GRAPH 64
#define F_IN    1536
#define H_DIM   1024
#define C_OUT   80
#define FUSE_D  1024
#define POOL_CHUNK 128
#define MLP1_KC 320   // 2560 / 8 k-chunks
#define SCAN_B  49    // ceil(N_NODES/1024)

typedef unsigned short u16;
typedef short s16x8 __attribute__((ext_vector_type(8)));
typedef float f32x4 __attribute__((ext_vector_type(4)));
typedef unsigned short u16x4 __attribute__((ext_vector_type(4)));
typedef unsigned short u16x8 __attribute__((ext_vector_type(8)));

// ---------- bf16 helpers (bit-level, RNE) ----------
__device__ __forceinline__ float bf2f(u16 u) {
    union { unsigned int i; float f; } v; v.i = ((unsigned int)u) << 16; return v.f;
}
__device__ __forceinline__ u16 f2bf(float f) {
    union { float f; unsigned int i; } v; v.f = f;
    unsigned int x = v.i;
    unsigned int r = (x + 0x7fffu + ((x >> 16) & 1u)) >> 16;
    return (u16)r;
}

// async global->LDS, 16 bytes per lane (lds dest must be linear in lane order)
__device__ __forceinline__ void load_lds16(const void* g, void* l) {
    __builtin_amdgcn_global_load_lds(
        (const __attribute__((address_space(1))) void*)g,
        (__attribute__((address_space(3))) void*)l, 16, 0, 0);
}

// ---------- graph prep kernels ----------
__global__ void k_deg(const int* __restrict__ dst, int* cnt) {
    int e = blockIdx.x * blockDim.x + threadIdx.x;
    if (e < N_EDGES) atomicAdd(&cnt[dst[e]], 1);
}

__global__ void k_cg(const int* __restrict__ batch, int* cG) {
    int i = blockIdx.x * blockDim.x + threadIdx.x;
    if (i < N_NODES) atomicAdd(&cG[batch[i]], 1);
}

// ---------- coalesced 3-kernel scan (replaces single-block strided k_scan) ----------
// bsum/boff live in the head of the col buffer (written only later by k_fill) --
// workspace footprint byte-identical to the last harness-passed layout.
// a: per-1024-block sums (coalesced loads, LDS tree reduce)
__global__ __launch_bounds__(1024) void k_scan_a(const int* __restrict__ cnt, int* __restrict__ bsum) {
    __shared__ int lds[1024];
    int t = threadIdx.x;
    int i = blockIdx.x * 1024 + t;
    lds[t] = (i < N_NODES) ? cnt[i] : 0;
    __syncthreads();
    for (int off = 512; off > 0; off >>= 1) {
        if (t < off) lds[t] += lds[t + off];
        __syncthreads();
    }
    if (t == 0) bsum[blockIdx.x] = lds[0];
}

// b: 1-wave exclusive scan of the SCAN_B block sums; also writes rowptr[N]
__global__ __launch_bounds__(64) void k_scan_b(const int* __restrict__ bsum,
                                               int* __restrict__ boff, int* __restrict__ rowptr) {
    int t = threadIdx.x;  // 64 lanes
    int v = (t < SCAN_B) ? bsum[t] : 0;
    for (int off = 1; off < 64; off <<= 1) {
        int u = __shfl_up(v, off);
        if (t >= off) v += u;           // inclusive scan
    }
    if (t < SCAN_B) boff[t] = v - bsum[t];   // exclusive
    if (t == SCAN_B - 1) rowptr[N_NODES] = v;
}

// c: per-block Hillis-Steele scan + coalesced writeback of rowptr and dis
__global__ __launch_bounds__(1024) void k_scan_c(const int* __restrict__ cnt, const int* __restrict__ boff,
                                                 int* __restrict__ rowptr, float* __restrict__ dis) {
    __shared__ int lds[1024];
    int t = threadIdx.x;
    int i = blockIdx.x * 1024 + t;
    int c = (i < N_NODES) ? cnt[i] : 0;
    lds[t] = c;
    __syncthreads();
    for (int off = 1; off < 1024; off <<= 1) {
        int u = (t >= off) ? lds[t - off] : 0;
        __syncthreads();
        lds[t] += u;
        __syncthreads();
    }
    if (i < N_NODES) {
        rowptr[i] = boff[blockIdx.x] + lds[t] - c;   // exclusive prefix
        dis[i] = rsqrtf((float)(c + 1));             // +1 self-loop
    }
}

__global__ void k_fill(const int* __restrict__ src, const int* __restrict__ dst,
                       const int* __restrict__ rowptr, int* cursor, int* col) {
    int e = blockIdx.x * blockDim.x + threadIdx.x;
    if (e < N_EDGES) {
        int d = dst[e];
        int p = atomicAdd(&cursor[d], 1);
        col[rowptr[d] + p] = src[e];
    }
}

// ---------- fp32 -> bf16 cast (vectorized) ----------
__global__ void k_cvt(const float* __restrict__ in, u16* __restrict__ out, long n) {
    long i = (long)blockIdx.x * blockDim.x + threadIdx.x;
    long stride = (long)gridDim.x * blockDim.x;
    for (long v = i * 4; v < n; v += stride * 4) {
        float4 f = *(const float4*)(in + v);
        u16x4 o = { f2bf(f.x), f2bf(f.y), f2bf(f.z), f2bf(f.w) };
        *(u16x4*)(out + v) = o;
    }
}

// W [K x Nn] fp32 -> Wt [Nn x K] bf16 (tiled transpose)
__global__ void k_trn(const float* __restrict__ W, u16* __restrict__ Wt, int K, int Nn) {
    __shared__ float tle[32][33];
    int n0 = blockIdx.x * 32, k0 = blockIdx.y * 32;
    int tx = threadIdx.x, ty = threadIdx.y;  // 32 x 8
    for (int i = ty; i < 32; i += 8)
        tle[i][tx] = W[(size_t)(k0 + i) * Nn + n0 + tx];
    __syncthreads();
    for (int i = ty; i < 32; i += 8)
        Wt[(size_t)(n0 + i) * K + k0 + tx] = f2bf(tle[tx][i]);
}

// ---------- MFMA GEMM: C[Mx1024] = A[MxK] @ Bt[1024xK]^T, all bf16, C bf16 ----------
// 256x256 block tile, BK=64, 512 threads = 8 waves (2M x 4N), per-wave 128x64.
// R1 body (control): depth-2 global_load_lds prefetch, counted vmcnt(8), raw
// s_barrier, T2 inverse-source swizzle, T5 setprio. Schedule variants (2-phase,
// 4-phase) measured identical -- GEMM parked pending new counter evidence.
__global__ __launch_bounds__(512) void gemm_bt(const u16* __restrict__ A,
                                               const u16* __restrict__ Bt,
                                               u16* __restrict__ C,
                                               int M, int Nn, int K) {
    __shared__ __attribute__((aligned(16))) u16 ldsA[2 * 2048 * 8];
    __shared__ __attribute__((aligned(16))) u16 ldsB[2 * 2048 * 8];

    int bid = blockIdx.x;
    int swz = (bid & 7) * 98 + (bid >> 3);
    int bN = swz & 3;          // 4 N-tiles (Nn = 1024)
    int bM = swz >> 2;         // 196 M-tiles

    int tid = threadIdx.x;
    int lane = tid & 63, wave = tid >> 6;
    int wm = wave >> 2, wn = wave & 3;     // 2 x 4 wave grid
    int qd = lane >> 4, lo = lane & 15;

    const u16* ga[4];
    const u16* gb[4];
#pragma unroll
    for (int r = 0; r < 4; ++r) {
        int c = r * 512 + tid;
        int row = c >> 3;
        int kc = (c & 7) ^ (row & 7);
        int gr = bM * 256 + row;
        if (gr > M - 1) gr = M - 1;        // clamp; garbage rows masked at store
        ga[r] = A + (size_t)gr * K + kc * 8;
        gb[r] = Bt + (size_t)(bN * 256 + row) * K + kc * 8;
    }

    auto stage = [&](int buf) {
        int base = buf * 16384;            // elems
#pragma unroll
        for (int r = 0; r < 4; ++r) {
            load_lds16(ga[r], &ldsA[base + (r * 512 + tid) * 8]);
            ga[r] += 64;                   // next K-tile (+128 B)
        }
#pragma unroll
        for (int r = 0; r < 4; ++r) {
            load_lds16(gb[r], &ldsB[base + (r * 512 + tid) * 8]);
            gb[r] += 64;
        }
    };

    const int NKT = K >> 6;                // 24 (K=1536) / 16 (K=1024)
    f32x4 acc[8][4] = {};

    stage(0);
    stage(1);

    for (int kt = 0; kt < NKT; ++kt) {
        int cur = kt & 1;
        if (kt < NKT - 1) {
            asm volatile("s_waitcnt vmcnt(8)" ::: "memory");  // tile kt landed; kt+1 in flight
        } else {
            asm volatile("s_waitcnt vmcnt(0)" ::: "memory");  // final peel: drain
        }
        __builtin_amdgcn_s_barrier();       // tile kt resident for all waves

        const u16* lA = ldsA + cur * 16384;
        const u16* lB = ldsB + cur * 16384;
#pragma unroll
        for (int ks = 0; ks < 2; ++ks) {    // two 32-wide K phases
            s16x8 af[8], bfv[4];
            int soff = (((ks << 2) + qd) ^ (lo & 7)) * 8;   // swizzled 16B slot
#pragma unroll
            for (int mf = 0; mf < 8; ++mf)
                af[mf] = *(const s16x8*)&lA[(wm * 128 + mf * 16 + lo) * 64 + soff];
#pragma unroll
            for (int nf = 0; nf < 4; ++nf)
                bfv[nf] = *(const s16x8*)&lB[(wn * 64 + nf * 16 + lo) * 64 + soff];
            __builtin_amdgcn_s_setprio(1);
#pragma unroll
            for (int mf = 0; mf < 8; ++mf)
#pragma unroll
                for (int nf = 0; nf < 4; ++nf)
                    acc[mf][nf] = __builtin_amdgcn_mfma_f32_16x16x32_bf16(
                        af[mf], bfv[nf], acc[mf][nf], 0, 0, 0);
            __builtin_amdgcn_s_setprio(0);
            __builtin_amdgcn_s_barrier();   // phase lock; after ks=1: reads done
        }
        if (kt + 2 < NKT) stage(cur);       // prefetch tile kt+2 into freed buffer
    }

    // C/D layout: col = lane&15, row = quad*4 + reg  [verified m89/m91]
#pragma unroll
    for (int mf = 0; mf < 8; ++mf) {
        int rowb = bM * 256 + wm * 128 + mf * 16 + qd * 4;
#pragma unroll
        for (int nf = 0; nf < 4; ++nf) {
            int colI = bN * 256 + wn * 64 + nf * 16 + lo;
            f32x4 a = acc[mf][nf];
#pragma unroll
            for (int reg = 0; reg < 4; ++reg) {
                int row = rowb + reg;
                if (row < M) C[(size_t)row * Nn + colI] = f2bf(a[reg]);
            }
        }
    }
}

// ---------- GCN aggregation, wave-per-node: 4 nodes/block, 64 lanes x 16 feats ----
// out[i] = relu(dis_i^2*h[i] + sum_e dis_i*dis_src*h[src] + b)
// Edge loop unrolled x2 with both row-gathers issued before accumulation:
// 4 independent 1-KB loads in flight per wave (vs compiler-serialized chain).
__global__ __launch_bounds__(256) void k_agg(const u16* __restrict__ hin, u16* __restrict__ hout,
                                             const int* __restrict__ rowptr, const int* __restrict__ col,
                                             const float* __restrict__ dis, const float* __restrict__ bias) {
    int w = threadIdx.x >> 6, lane = threadIdx.x & 63;
    int i = blockIdx.x * 4 + w;            // N_NODES % 4 == 0
    float di = dis[i];
    int beg = rowptr[i], end = rowptr[i + 1];
    const u16* hrow = hin + (size_t)i * H_DIM + lane * 16;
    u16x8 v0 = *(const u16x8*)hrow;
    u16x8 v1 = *(const u16x8*)(hrow + 8);
    float w0 = di * di;
    float acc[16];
#pragma unroll
    for (int j = 0; j < 8; j++) { acc[j] = w0 * bf2f(v0[j]); acc[8 + j] = w0 * bf2f(v1[j]); }
    int e = beg;
    for (; e + 2 <= end; e += 2) {
        int s0 = col[e], s1 = col[e + 1];   // wave-uniform
        float g0 = di * dis[s0], g1 = di * dis[s1];
        const u16* n0 = hin + (size_t)s0 * H_DIM + lane * 16;
        const u16* n1 = hin + (size_t)s1 * H_DIM + lane * 16;
        u16x8 a0 = *(const u16x8*)n0;
        u16x8 a1 = *(const u16x8*)(n0 + 8);
        u16x8 b0 = *(const u16x8*)n1;
        u16x8 b1 = *(const u16x8*)(n1 + 8);
#pragma unroll
        for (int j = 0; j < 8; j++) {
            acc[j]     += g0 * bf2f(a0[j]) + g1 * bf2f(b0[j]);
            acc[8 + j] += g0 * bf2f(a1[j]) + g1 * bf2f(b1[j]);
        }
    }
    if (e < end) {
        int s = col[e];
        float wgt = di * dis[s];
        const u16* nrow = hin + (size_t)s * H_DIM + lane * 16;
        u16x8 u0 = *(const u16x8*)nrow;
        u16x8 u1 = *(const u16x8*)(nrow + 8);
#pragma unroll
        for (int j = 0; j < 8; j++) { acc[j] += wgt * bf2f(u0[j]); acc[8 + j] += wgt * bf2f(u1[j]); }
    }
    const float* bp = bias + lane * 16;
    u16x8 o0, o1;
#pragma unroll
    for (int j = 0; j < 8; j++) {
        o0[j] = f2bf(fmaxf(acc[j] + bp[j], 0.f));
        o1[j] = f2bf(fmaxf(acc[8 + j] + bp[8 + j], 0.f));
    }
    u16* orow = hout + (size_t)i * H_DIM + lane * 16;
    *(u16x8*)orow = o0;
    *(u16x8*)(orow + 8) = o1;
}

// ---------- mean pool: chunked nodes, register segment-accumulate, atomic flush ----------
__global__ __launch_bounds__(256) void k_pool(const u16* __restrict__ h, const int* __restrict__ batch,
                                              float* __restrict__ pooled) {
    int t = threadIdx.x;
    int n0 = blockIdx.x * POOL_CHUNK;
    int n1 = min(n0 + POOL_CHUNK, N_NODES);
    float a0 = 0.f, a1 = 0.f, a2 = 0.f, a3 = 0.f;
    int curg = batch[n0];
    for (int n = n0; n < n1; ++n) {
        int g = batch[n];  // block-uniform
        if (g != curg) {   // uniform branch (rare: ~1-2 per block)
            float* p = &pooled[(size_t)curg * H_DIM + t * 4];
            atomicAdd(p + 0, a0); atomicAdd(p + 1, a1);
            atomicAdd(p + 2, a2); atomicAdd(p + 3, a3);
            a0 = a1 = a2 = a3 = 0.f;
            curg = g;
        }
        u16x4 v = *(const u16x4*)&h[(size_t)n * H_DIM + t * 4];
        a0 += bf2f(v[0]); a1 += bf2f(v[1]); a2 += bf2f(v[2]); a3 += bf2f(v[3]);
    }
    float* p = &pooled[(size_t)curg * H_DIM + t * 4];
    atomicAdd(p + 0, a0); atomicAdd(p + 1, a1);
    atomicAdd(p + 2, a2); atomicAdd(p + 3, a3);
}

// ---------- MLP head layer 1, split-K with atomic accumulation ----------
__global__ __launch_bounds__(256) void k_mlp1(const float* __restrict__ gx, const float* __restrict__ pooled,
                                              const int* __restrict__ cG,
                                              const float* __restrict__ fw1, float* __restrict__ hid) {
    __shared__ float comb[4 * MLP1_KC];
    int gq = blockIdx.x, jq = blockIdx.y, kq = blockIdx.z, t = threadIdx.x;
    int kbeg = kq * MLP1_KC;
    for (int idx = t; idx < 4 * MLP1_KC; idx += 256) {
        int gl = idx / MLP1_KC, kk = idx % MLP1_KC;
        int k = kbeg + kk;
        int g = gq * 4 + gl;
        float v;
        if (k < F_IN) v = gx[(size_t)g * F_IN + k];
        else v = pooled[(size_t)g * H_DIM + (k - F_IN)] / (float)max(cG[g], 1);
        comb[idx] = v;
    }
    __syncthreads();
    int j = jq * 256 + t;
    float a0 = 0, a1 = 0, a2 = 0, a3 = 0;
    for (int kk = 0; kk < MLP1_KC; ++kk) {
        float w = fw1[(size_t)(kbeg + kk) * FUSE_D + j];  // coalesced across lanes
        a0 += comb[kk] * w;
        a1 += comb[MLP1_KC + kk] * w;
        a2 += comb[2 * MLP1_KC + kk] * w;
        a3 += comb[3 * MLP1_KC + kk] * w;
    }
    atomicAdd(&hid[(size_t)(gq * 4 + 0) * FUSE_D + j], a0);
    atomicAdd(&hid[(size_t)(gq * 4 + 1) * FUSE_D + j], a1);
    atomicAdd(&hid[(size_t)(gq * 4 + 2) * FUSE_D + j], a2);
    atomicAdd(&hid[(size_t)(gq * 4 + 3) * FUSE_D + j], a3);
}

__global__ __launch_bounds__(128) void k_mlp2(const float* __restrict__ hid, const float* __restrict__ fb1,
                                              const float* __restrict__ fw2,
                                              const float* __restrict__ fb2, float* __restrict__ out) {
    __shared__ float hh[FUSE_D];
    int g = blockIdx.x, t = threadIdx.x;
    for (int idx = t; idx < FUSE_D; idx += 128)
        hh[idx] = fmaxf(hid[(size_t)g * FUSE_D + idx] + fb1[idx], 0.f);  // fused bias+relu
    __syncthreads();
    if (t < C_OUT) {
        float acc = fb2[t];
        for (int k = 0; k < FUSE_D; ++k) acc += hh[k] * fw2[k * C_OUT + t];
        out[g * C_OUT + t] = acc;
    }
}

extern "C" void kernel_launch(void* const* d_in, const int* in_sizes, int n_in,
                              void* d_out, int out_size, void* d_ws, size_t ws_size,
                              hipStream_t stream) {
    (void)in_sizes; (void)n_in; (void)out_size;
    const float* gx    = (const float*)d_in[0];
    const float* x     = (const float*)d_in[1];
    const int*   ei    = (const int*)d_in[2];
    const int*   batch = (const int*)d_in[3];
    const float* W1    = (const float*)d_in[4];
    const float* b1    = (const float*)d_in[5];
    const float* W2    = (const float*)d_in[6];
    const float* b2    = (const float*)d_in[7];
    const float* fw1   = (const float*)d_in[8];
    const float* fb1   = (const float*)d_in[9];
    const float* fw2   = (const float*)d_in[10];
    const float* fb2   = (const float*)d_in[11];
    float* out = (float*)d_out;
    const int* src = ei;
    const int* dst = ei + N_EDGES;

    // workspace layout (~366 MB total, IDENTICAL to last passing layout); zero zone at end
    char* ws = (char*)d_ws;
    size_t off = 0;
    auto alloc = [&](size_t bytes) -> char* {
        char* p = ws + off;
        off += (bytes + 255) & ~(size_t)255;
        return p;
    };
    u16*  xb     = (u16*)alloc((size_t)N_NODES * F_IN * 2);   // reused as h2b
    u16*  h0b    = (u16*)alloc((size_t)N_NODES * H_DIM * 2);  // reused as h3b
    u16*  h1b    = (u16*)alloc((size_t)N_NODES * H_DIM * 2);
    u16*  W1T    = (u16*)alloc((size_t)H_DIM * F_IN * 2);
    u16*  W2T    = (u16*)alloc((size_t)H_DIM * H_DIM * 2);
    float* dis    = (float*)alloc((size_t)N_NODES * 4);
    int* rowptr   = (int*)alloc((size_t)(N_NODES + 1) * 4);
    int* col      = (int*)alloc((size_t)N_EDGES * 4);
    // ---- zero zone start ----
    int* cnt      = (int*)alloc((size_t)N_NODES * 4);
    int* cursor   = (int*)alloc((size_t)N_NODES * 4);
    int* cG       = (int*)alloc(256);
    float* pooled = (float*)alloc((size_t)N_GRAPH * H_DIM * 4);
    float* hid    = (float*)alloc((size_t)N_GRAPH * FUSE_D * 4);
    u16* h2b = xb;
    u16* h3b = h0b;
    // scan scratch aliased into col[] head (col written only later by k_fill)
    int* bsum = col;        // 49 ints
    int* boff = col + 64;   // 49 ints
    (void)ws_size;

    // zero the accumulation zone (ws is poisoned 0xAA before every call)
    size_t zbytes = (size_t)((char*)(hid + N_GRAPH * FUSE_D) - (char*)cnt);
    hipMemsetAsync(cnt, 0, zbytes, stream);

    // graph prep
    k_deg<<<(N_EDGES + 255) / 256, 256, 0, stream>>>(dst, cnt);
    k_cg<<<(N_NODES + 255) / 256, 256, 0, stream>>>(batch, cG);
    k_scan_a<<<SCAN_B, 1024, 0, stream>>>(cnt, bsum);
    k_scan_b<<<1, 64, 0, stream>>>(bsum, boff, rowptr);
    k_scan_c<<<SCAN_B, 1024, 0, stream>>>(cnt, boff, rowptr, dis);
    k_fill<<<(N_EDGES + 255) / 256, 256, 0, stream>>>(src, dst, rowptr, cursor, col);

    // casts / weight transposes
    k_cvt<<<4096, 256, 0, stream>>>(x, xb, (long)N_NODES * F_IN);
    k_trn<<<dim3(H_DIM / 32, F_IN / 32), dim3(32, 8), 0, stream>>>(W1, W1T, F_IN, H_DIM);
    k_trn<<<dim3(H_DIM / 32, H_DIM / 32), dim3(32, 8), 0, stream>>>(W2, W2T, H_DIM, H_DIM);

    // GEMM grid: 196 M-tiles x 4 N-tiles = 784 blocks (784 % 8 == 0 -> clean XCD swizzle)
    const int GEMM_BLOCKS = ((N_NODES + 255) / 256) * (H_DIM / 256);   // 784

    // layer 1
    gemm_bt<<<GEMM_BLOCKS, 512, 0, stream>>>(xb, W1T, h0b, N_NODES, H_DIM, F_IN);
    k_agg<<<N_NODES / 4, 256, 0, stream>>>(h0b, h1b, rowptr, col, dis, b1);
    // layer 2
    gemm_bt<<<GEMM_BLOCKS, 512, 0, stream>>>(h1b, W2T, h2b, N_NODES, H_DIM, H_DIM);
    k_agg<<<N_NODES / 4, 256, 0, stream>>>(h2b, h3b, rowptr, col, dis, b2);

    // pool + head
    k_pool<<<(N_NODES + POOL_CHUNK - 1) / POOL_CHUNK, 256, 0, stream>>>(h3b, batch, pooled);
    k_mlp1<<<dim3(N_GRAPH / 4, FUSE_D / 256, 8), 256, 0, stream>>>(gx, pooled, cG, fw1, hid);
    k_mlp2<<<N_GRAPH, 128, 0, stream>>>(hid, fb1, fw2, fb2, out);
}